// Round 2
// baseline (1726.784 us; speedup 1.0000x reference)
//
#include <hip/hip_runtime.h>
#include <hip/hip_bf16.h>

// 2-layer tanh RNN, T=2048, B=4096, I=3, H=5.
// One thread per batch chain; 4096 threads = 64 wave64 waves.
// Serial-issue-bound: wall = 2048 steps * per-step wave issue cost.
// tanh(z) = 1 - 2*rcp(1+exp2(S*z)) with weights pre-scaled by S=2*log2(e).
//
// Dtype hedge: harness may store f32 (per reference dtype) or bf16 (bf16
// dataset flavor). detect_dtype reads x as bf16 halves: f32 storage yields
// garbage exponents (|v|>1e4 or NaN) with overwhelming probability; bf16
// N(0,1) data never does. Flag lives in d_ws, written every launch.

#define SEQ_T 2048
#define BATCH 4096
#define ISZ 3
#define HSZ 5

typedef __hip_bfloat16 bf16;

__global__ void detect_dtype(const unsigned short* __restrict__ xraw,
                             int* __restrict__ flag) {
    if (threadIdx.x == 0 && blockIdx.x == 0) {
        int f32like = 0;
        for (int i = 0; i < 256; i++) {
            unsigned int u = ((unsigned int)xraw[i]) << 16;
            float v = __uint_as_float(u);
            if (!(__builtin_fabsf(v) < 1.0e4f)) f32like = 1;  // huge/inf/NaN
        }
        *flag = f32like;
    }
}

template<bool F32>
__device__ __forceinline__ float ld(const void* p, size_t i) {
    if constexpr (F32) return ((const float*)p)[i];
    else return __bfloat162float(((const bf16*)p)[i]);
}
template<bool F32>
__device__ __forceinline__ void st(void* p, size_t i, float v) {
    if constexpr (F32) ((float*)p)[i] = v;
    else ((bf16*)p)[i] = __float2bfloat16(v);
}

template<bool F32>
__device__ __forceinline__ void rnn_body(
    const void* __restrict__ x, const void* __restrict__ hx,
    const void* __restrict__ w_ih0, const void* __restrict__ w_hh0,
    const void* __restrict__ b_ih0, const void* __restrict__ b_hh0,
    const void* __restrict__ w_ih1, const void* __restrict__ w_hh1,
    const void* __restrict__ b_ih1, const void* __restrict__ b_hh1,
    void* __restrict__ out)
{
    const int b = blockIdx.x * 64 + threadIdx.x;   // chain id, 0..4095
    const float S = 2.8853900817779268f;           // 2*log2(e)

    // ---- uniform weight preload (hoisted) ----
    float wih0[HSZ][ISZ], whh0[HSZ][HSZ], bias0[HSZ];
    float wih1[HSZ][HSZ], whh1[HSZ][HSZ], bias1[HSZ];
#pragma unroll
    for (int j = 0; j < HSZ; j++) {
        bias0[j] = S * (ld<F32>(b_ih0, j) + ld<F32>(b_hh0, j));
        bias1[j] = S * (ld<F32>(b_ih1, j) + ld<F32>(b_hh1, j));
#pragma unroll
        for (int i = 0; i < ISZ; i++)
            wih0[j][i] = S * ld<F32>(w_ih0, j * ISZ + i);
#pragma unroll
        for (int k = 0; k < HSZ; k++) {
            whh0[j][k] = S * ld<F32>(w_hh0, j * HSZ + k);
            wih1[j][k] = S * ld<F32>(w_ih1, j * HSZ + k);
            whh1[j][k] = S * ld<F32>(w_hh1, j * HSZ + k);
        }
    }

    // ---- recurrent state ----
    float h0[HSZ], h1[HSZ];
#pragma unroll
    for (int j = 0; j < HSZ; j++) {
        h0[j] = ld<F32>(hx, (size_t)b * HSZ + j);
        h1[j] = ld<F32>(hx, (size_t)BATCH * HSZ + b * HSZ + j);
    }

    // ---- x prefetch pipeline, depth 3 (HBM latency ~900cyc > step cost) ----
    const size_t xbase = (size_t)b * ISZ;
    float xA[ISZ], xB[ISZ], xC[ISZ];
#pragma unroll
    for (int i = 0; i < ISZ; i++) {
        xA[i] = ld<F32>(x, xbase + (size_t)0 * BATCH * ISZ + i);
        xB[i] = ld<F32>(x, xbase + (size_t)1 * BATCH * ISZ + i);
        xC[i] = ld<F32>(x, xbase + (size_t)2 * BATCH * ISZ + i);
    }

    for (int t = 0; t < SEQ_T; t++) {
        // layer 0: h0' = tanh(x*Wih0^T + h0*Whh0^T + b)   (pre-scaled by S)
        float h0n[HSZ];
#pragma unroll
        for (int j = 0; j < HSZ; j++) {
            float a = bias0[j];
#pragma unroll
            for (int i = 0; i < ISZ; i++) a = fmaf(xA[i], wih0[j][i], a);
#pragma unroll
            for (int k = 0; k < HSZ; k++) a = fmaf(h0[k], whh0[j][k], a);
            float e = __builtin_amdgcn_exp2f(a);                 // e^{2z}
            h0n[j] = fmaf(-2.0f, __builtin_amdgcn_rcpf(1.0f + e), 1.0f);
        }
#pragma unroll
        for (int j = 0; j < HSZ; j++) h0[j] = h0n[j];

        // layer 1: h1' = tanh(h0'*Wih1^T + h1*Whh1^T + b)
        float h1n[HSZ];
#pragma unroll
        for (int j = 0; j < HSZ; j++) {
            float a = bias1[j];
#pragma unroll
            for (int k = 0; k < HSZ; k++) a = fmaf(h0[k], wih1[j][k], a);
#pragma unroll
            for (int k = 0; k < HSZ; k++) a = fmaf(h1[k], whh1[j][k], a);
            float e = __builtin_amdgcn_exp2f(a);
            h1n[j] = fmaf(-2.0f, __builtin_amdgcn_rcpf(1.0f + e), 1.0f);
        }
#pragma unroll
        for (int j = 0; j < HSZ; j++) h1[j] = h1n[j];

        // store out[t][b][:]
        const size_t obase = (size_t)t * BATCH * HSZ + (size_t)b * HSZ;
#pragma unroll
        for (int j = 0; j < HSZ; j++) st<F32>(out, obase + j, h1[j]);

        // rotate x pipeline, prefetch t+3
#pragma unroll
        for (int i = 0; i < ISZ; i++) { xA[i] = xB[i]; xB[i] = xC[i]; }
        if (t + 3 < SEQ_T) {
            const size_t xq = xbase + (size_t)(t + 3) * BATCH * ISZ;
#pragma unroll
            for (int i = 0; i < ISZ; i++) xC[i] = ld<F32>(x, xq + i);
        }
    }

    // h_n = [h0_final, h1_final], appended after out[T,B,H]
    const size_t hnb = (size_t)SEQ_T * BATCH * HSZ;
#pragma unroll
    for (int j = 0; j < HSZ; j++) {
        st<F32>(out, hnb + (size_t)b * HSZ + j, h0[j]);
        st<F32>(out, hnb + (size_t)BATCH * HSZ + (size_t)b * HSZ + j, h1[j]);
    }
}

__global__ __launch_bounds__(64, 1)
void rnn2_fused(const void* __restrict__ x, const void* __restrict__ hx,
                const void* __restrict__ w_ih0, const void* __restrict__ w_hh0,
                const void* __restrict__ b_ih0, const void* __restrict__ b_hh0,
                const void* __restrict__ w_ih1, const void* __restrict__ w_hh1,
                const void* __restrict__ b_ih1, const void* __restrict__ b_hh1,
                void* __restrict__ out, const int* __restrict__ flag)
{
    if (*flag) {
        rnn_body<true>(x, hx, w_ih0, w_hh0, b_ih0, b_hh0,
                       w_ih1, w_hh1, b_ih1, b_hh1, out);
    } else {
        rnn_body<false>(x, hx, w_ih0, w_hh0, b_ih0, b_hh0,
                        w_ih1, w_hh1, b_ih1, b_hh1, out);
    }
}

extern "C" void kernel_launch(void* const* d_in, const int* in_sizes, int n_in,
                              void* d_out, int out_size, void* d_ws, size_t ws_size,
                              hipStream_t stream) {
    int* flag = (int*)d_ws;
    detect_dtype<<<1, 64, 0, stream>>>((const unsigned short*)d_in[0], flag);
    rnn2_fused<<<BATCH / 64, 64, 0, stream>>>(
        d_in[0], d_in[1], d_in[2], d_in[3], d_in[4], d_in[5],
        d_in[6], d_in[7], d_in[8], d_in[9], d_out, flag);
}

// Round 3
// 1029.680 us; speedup vs baseline: 1.6770x; 1.6770x over previous
//
#include <hip/hip_runtime.h>
#include <hip/hip_bf16.h>

// 2-layer tanh RNN, T=2048, B=4096, I=3, H=5. f32 storage (confirmed R2:
// WRITE_SIZE == out_size*4B). One thread per chain; 64 wave64 waves.
//
// R2 post-mortem: 1808 cyc/step with only ~9% per-CU VALU busy. Causes:
// (a) VGPR_Count=68 -> compiler rematerialized ~90 uniform weight loads
//     per step instead of keeping them resident;
// (b) per-step global stores whose data regs are reused next step ->
//     s_waitcnt store-drain (~1-1.5k cyc) on the critical path every step.
// Fixes: pin weights in VGPRs (asm "+v" barrier), K=8-step register output
// buffer (store reuse distance = 8 steps), block-granular x double buffer
// (load->use distance = 8 steps, waits never include stores in vmcnt FIFO).

#define SEQ_T 2048
#define BATCH 4096
#define ISZ 3
#define HSZ 5
#define KB 8                    // steps per output/x block
#define NBLK (SEQ_T / KB)

#define PIN(v) asm volatile("" : "+v"(v))

__global__ __launch_bounds__(64, 1)
void rnn2_fused(const float* __restrict__ x, const float* __restrict__ hx,
                const float* __restrict__ w_ih0, const float* __restrict__ w_hh0,
                const float* __restrict__ b_ih0, const float* __restrict__ b_hh0,
                const float* __restrict__ w_ih1, const float* __restrict__ w_hh1,
                const float* __restrict__ b_ih1, const float* __restrict__ b_hh1,
                float* __restrict__ out)
{
    const int b = blockIdx.x * 64 + threadIdx.x;   // chain id, 0..4095
    const float S = 2.8853900817779268f;           // 2*log2(e): tanh(z)=1-2*rcp(1+exp2(S*z))

    // ---- uniform weights, pre-scaled by S, pinned resident in VGPRs ----
    float wih0[HSZ][ISZ], whh0[HSZ][HSZ], bias0[HSZ];
    float wih1[HSZ][HSZ], whh1[HSZ][HSZ], bias1[HSZ];
#pragma unroll
    for (int j = 0; j < HSZ; j++) {
        bias0[j] = S * (b_ih0[j] + b_hh0[j]);  PIN(bias0[j]);
        bias1[j] = S * (b_ih1[j] + b_hh1[j]);  PIN(bias1[j]);
#pragma unroll
        for (int i = 0; i < ISZ; i++) { wih0[j][i] = S * w_ih0[j * ISZ + i]; PIN(wih0[j][i]); }
#pragma unroll
        for (int k = 0; k < HSZ; k++) {
            whh0[j][k] = S * w_hh0[j * HSZ + k]; PIN(whh0[j][k]);
            wih1[j][k] = S * w_ih1[j * HSZ + k]; PIN(wih1[j][k]);
            whh1[j][k] = S * w_hh1[j * HSZ + k]; PIN(whh1[j][k]);
        }
    }

    // ---- recurrent state ----
    float h0[HSZ], h1[HSZ];
#pragma unroll
    for (int j = 0; j < HSZ; j++) {
        h0[j] = hx[(size_t)b * HSZ + j];
        h1[j] = hx[(size_t)BATCH * HSZ + (size_t)b * HSZ + j];
    }

    const float* xp = x + (size_t)b * ISZ;
    float* op = out + (size_t)b * HSZ;

    // ---- x double buffer at block granularity ----
    float xcur[KB][ISZ], xnxt[KB][ISZ];
#pragma unroll
    for (int tt = 0; tt < KB; tt++)
#pragma unroll
        for (int i = 0; i < ISZ; i++)
            xcur[tt][i] = xp[(size_t)tt * BATCH * ISZ + i];

    float obuf[KB][HSZ];

    for (int blk = 0; blk < NBLK; blk++) {
        // prefetch next block's x (consumed one full block later)
        if (blk + 1 < NBLK) {
            const float* xq = xp + (size_t)(blk + 1) * KB * BATCH * ISZ;
#pragma unroll
            for (int tt = 0; tt < KB; tt++)
#pragma unroll
                for (int i = 0; i < ISZ; i++)
                    xnxt[tt][i] = xq[(size_t)tt * BATCH * ISZ + i];
        }

#pragma unroll
        for (int tt = 0; tt < KB; tt++) {
            // layer 0: h0' = tanh(x*Wih0^T + h0*Whh0^T + b)  (pre-scaled by S)
            float h0n[HSZ];
#pragma unroll
            for (int j = 0; j < HSZ; j++) {
                float a = bias0[j], c = 0.0f;
                a = fmaf(xcur[tt][0], wih0[j][0], a);
                c = fmaf(xcur[tt][1], wih0[j][1], c);
                a = fmaf(xcur[tt][2], wih0[j][2], a);
                c = fmaf(h0[0], whh0[j][0], c);
                a = fmaf(h0[1], whh0[j][1], a);
                c = fmaf(h0[2], whh0[j][2], c);
                a = fmaf(h0[3], whh0[j][3], a);
                c = fmaf(h0[4], whh0[j][4], c);
                a += c;
                float e = __builtin_amdgcn_exp2f(a);
                h0n[j] = fmaf(-2.0f, __builtin_amdgcn_rcpf(1.0f + e), 1.0f);
            }
#pragma unroll
            for (int j = 0; j < HSZ; j++) h0[j] = h0n[j];

            // layer 1: h1' = tanh(h0'*Wih1^T + h1*Whh1^T + b)
            float h1n[HSZ];
#pragma unroll
            for (int j = 0; j < HSZ; j++) {
                float a = bias1[j], c = 0.0f;
                a = fmaf(h0[0], wih1[j][0], a);
                c = fmaf(h0[1], wih1[j][1], c);
                a = fmaf(h0[2], wih1[j][2], a);
                c = fmaf(h0[3], wih1[j][3], c);
                a = fmaf(h0[4], wih1[j][4], a);
                c = fmaf(h1[0], whh1[j][0], c);
                a = fmaf(h1[1], whh1[j][1], a);
                c = fmaf(h1[2], whh1[j][2], c);
                a = fmaf(h1[3], whh1[j][3], a);
                c = fmaf(h1[4], whh1[j][4], c);
                a += c;
                float e = __builtin_amdgcn_exp2f(a);
                h1n[j] = fmaf(-2.0f, __builtin_amdgcn_rcpf(1.0f + e), 1.0f);
            }
#pragma unroll
            for (int j = 0; j < HSZ; j++) { h1[j] = h1n[j]; obuf[tt][j] = h1n[j]; }
        }

        // flush output block: store-data regs (obuf) not reused for 8 steps
        float* ob = op + (size_t)blk * KB * BATCH * HSZ;
#pragma unroll
        for (int tt = 0; tt < KB; tt++)
#pragma unroll
            for (int j = 0; j < HSZ; j++)
                ob[(size_t)tt * BATCH * HSZ + j] = obuf[tt][j];

        // rotate x double buffer (v_movs; waits only on this block's loads,
        // which sit BEHIND the flush stores in the vmcnt FIFO)
#pragma unroll
        for (int tt = 0; tt < KB; tt++)
#pragma unroll
            for (int i = 0; i < ISZ; i++)
                xcur[tt][i] = xnxt[tt][i];
    }

    // h_n = [h0_final, h1_final], appended after out[T,B,H]
    float* hn = out + (size_t)SEQ_T * BATCH * HSZ;
#pragma unroll
    for (int j = 0; j < HSZ; j++) {
        hn[(size_t)b * HSZ + j] = h0[j];
        hn[(size_t)BATCH * HSZ + (size_t)b * HSZ + j] = h1[j];
    }
}

extern "C" void kernel_launch(void* const* d_in, const int* in_sizes, int n_in,
                              void* d_out, int out_size, void* d_ws, size_t ws_size,
                              hipStream_t stream) {
    rnn2_fused<<<BATCH / 64, 64, 0, stream>>>(
        (const float*)d_in[0], (const float*)d_in[1],
        (const float*)d_in[2], (const float*)d_in[3],
        (const float*)d_in[4], (const float*)d_in[5],
        (const float*)d_in[6], (const float*)d_in[7],
        (const float*)d_in[8], (const float*)d_in[9],
        (float*)d_out);
}

// Round 5
// 1025.822 us; speedup vs baseline: 1.6833x; 1.0038x over previous
//
#include <hip/hip_runtime.h>
#include <hip/hip_bf16.h>

// 2-layer tanh RNN, T=2048, B=4096, I=3, H=5. f32 storage.
// One thread per chain; 64 wave64 waves, 1 wave/CU -> zero latency hiding,
// so the whole game is (a) nothing in scratch, (b) no vmcnt waits on the
// critical path, (c) minimum VALU issue per step.
//
// R4 post-mortem: correctness bug — layer-1 recurrence wrote h1[j] inside
// the j-loop, so later j's read the NEW h1 (Gauss-Seidel). Restored h1n[]
// staging + post-loop commit (Jacobi, matches reference).
// Structure kept from R4: 75 matrix weights in SGPRs via readfirstlane
// (wave-uniform values; v_fma reads 1 SGPR legally); x in-place modulo
// buffer (reuse distance 8 steps); obuf double-buffered by block parity
// (store-data reuse distance 16 steps -> store-ack off critical path).

#define SEQ_T 2048
#define BATCH 4096
#define ISZ 3
#define HSZ 5
#define KB 8                    // steps per block
#define NBLK (SEQ_T / KB)

__device__ __forceinline__ float rfl(float v) {   // force to SGPR
    return __int_as_float(__builtin_amdgcn_readfirstlane(__float_as_int(v)));
}

__global__ __launch_bounds__(64, 1)
void rnn2_fused(const float* __restrict__ x, const float* __restrict__ hx,
                const float* __restrict__ w_ih0, const float* __restrict__ w_hh0,
                const float* __restrict__ b_ih0, const float* __restrict__ b_hh0,
                const float* __restrict__ w_ih1, const float* __restrict__ w_hh1,
                const float* __restrict__ b_ih1, const float* __restrict__ b_hh1,
                float* __restrict__ out)
{
    const int b = blockIdx.x * 64 + threadIdx.x;   // chain id, 0..4095
    const float S = 2.8853900817779268f;           // 2*log2(e): tanh(z)=1-2*rcp(1+exp2(S*z))

    // ---- weights: big matrices scaled then forced into SGPRs ----
    float whh0[HSZ][HSZ], wih1[HSZ][HSZ], whh1[HSZ][HSZ];   // SGPR-resident
    float wih0[HSZ][ISZ], bias0[HSZ], bias1[HSZ];           // VGPR (acc seeds)
#pragma unroll
    for (int j = 0; j < HSZ; j++) {
        bias0[j] = S * (b_ih0[j] + b_hh0[j]);
        bias1[j] = S * (b_ih1[j] + b_hh1[j]);
#pragma unroll
        for (int i = 0; i < ISZ; i++) wih0[j][i] = S * w_ih0[j * ISZ + i];
#pragma unroll
        for (int k = 0; k < HSZ; k++) {
            whh0[j][k] = rfl(S * w_hh0[j * HSZ + k]);
            wih1[j][k] = rfl(S * w_ih1[j * HSZ + k]);
            whh1[j][k] = rfl(S * w_hh1[j * HSZ + k]);
        }
    }

    // ---- recurrent state ----
    float h0[HSZ], h1[HSZ];
#pragma unroll
    for (int j = 0; j < HSZ; j++) {
        h0[j] = hx[(size_t)b * HSZ + j];
        h1[j] = hx[(size_t)BATCH * HSZ + (size_t)b * HSZ + j];
    }

    const float* xp = x + (size_t)b * ISZ;
    float* op = out + (size_t)b * HSZ;

    // ---- x modulo buffer: slot tt consumed, then refilled for next block ----
    float xbuf[KB][ISZ];
#pragma unroll
    for (int tt = 0; tt < KB; tt++)
#pragma unroll
        for (int i = 0; i < ISZ; i++)
            xbuf[tt][i] = xp[(size_t)tt * BATCH * ISZ + i];

    // ---- output staging, double-buffered by block parity ----
    float obuf[2][KB][HSZ];

    for (int blk = 0; blk < NBLK; blk++) {
        float (*ob)[HSZ] = obuf[blk & 1];
        // prefetch base for block+1 (clamped: last block harmlessly reloads)
        const int pf = (blk + 1 < NBLK) ? (blk + 1) * KB : blk * KB;

#pragma unroll
        for (int tt = 0; tt < KB; tt++) {
            // consume this step's x, then refill the slot (reuse dist = 8 steps)
            const float xv0 = xbuf[tt][0], xv1 = xbuf[tt][1], xv2 = xbuf[tt][2];
            const float* xq = xp + (size_t)(pf + tt) * BATCH * ISZ;
            xbuf[tt][0] = xq[0]; xbuf[tt][1] = xq[1]; xbuf[tt][2] = xq[2];

            // layer 0: h0' = tanh(x*Wih0^T + h0*Whh0^T + b)  (pre-scaled by S)
            float h0n[HSZ];
#pragma unroll
            for (int j = 0; j < HSZ; j++) {
                float a = bias0[j], c = 0.0f;
                a = fmaf(xv0, wih0[j][0], a);
                c = fmaf(xv1, wih0[j][1], c);
                a = fmaf(xv2, wih0[j][2], a);
                c = fmaf(h0[0], whh0[j][0], c);
                a = fmaf(h0[1], whh0[j][1], a);
                c = fmaf(h0[2], whh0[j][2], c);
                a = fmaf(h0[3], whh0[j][3], a);
                c = fmaf(h0[4], whh0[j][4], c);
                a += c;
                float e = __builtin_amdgcn_exp2f(a);
                h0n[j] = fmaf(-2.0f, __builtin_amdgcn_rcpf(1.0f + e), 1.0f);
            }
#pragma unroll
            for (int j = 0; j < HSZ; j++) h0[j] = h0n[j];

            // layer 1: h1' = tanh(h0'*Wih1^T + h1*Whh1^T + b)
            // NB: must read PREVIOUS h1 for all j -> stage in h1n, commit after.
            float h1n[HSZ];
#pragma unroll
            for (int j = 0; j < HSZ; j++) {
                float a = bias1[j], c = 0.0f;
                a = fmaf(h0[0], wih1[j][0], a);
                c = fmaf(h0[1], wih1[j][1], c);
                a = fmaf(h0[2], wih1[j][2], a);
                c = fmaf(h0[3], wih1[j][3], c);
                a = fmaf(h0[4], wih1[j][4], a);
                c = fmaf(h1[0], whh1[j][0], c);
                a = fmaf(h1[1], whh1[j][1], a);
                c = fmaf(h1[2], whh1[j][2], c);
                a = fmaf(h1[3], whh1[j][3], a);
                c = fmaf(h1[4], whh1[j][4], c);
                a += c;
                float e = __builtin_amdgcn_exp2f(a);
                h1n[j] = fmaf(-2.0f, __builtin_amdgcn_rcpf(1.0f + e), 1.0f);
            }
#pragma unroll
            for (int j = 0; j < HSZ; j++) { h1[j] = h1n[j]; ob[tt][j] = h1n[j]; }
        }

        // flush this block (data regs not reused for 16 steps: parity dbuf)
        float* obase = op + (size_t)blk * KB * BATCH * HSZ;
#pragma unroll
        for (int tt = 0; tt < KB; tt++)
#pragma unroll
            for (int j = 0; j < HSZ; j++)
                obase[(size_t)tt * BATCH * HSZ + j] = ob[tt][j];
    }

    // h_n = [h0_final, h1_final], appended after out[T,B,H]
    float* hn = out + (size_t)SEQ_T * BATCH * HSZ;
#pragma unroll
    for (int j = 0; j < HSZ; j++) {
        hn[(size_t)b * HSZ + j] = h0[j];
        hn[(size_t)BATCH * HSZ + (size_t)b * HSZ + j] = h1[j];
    }
}

extern "C" void kernel_launch(void* const* d_in, const int* in_sizes, int n_in,
                              void* d_out, int out_size, void* d_ws, size_t ws_size,
                              hipStream_t stream) {
    rnn2_fused<<<BATCH / 64, 64, 0, stream>>>(
        (const float*)d_in[0], (const float*)d_in[1],
        (const float*)d_in[2], (const float*)d_in[3],
        (const float*)d_in[4], (const float*)d_in[5],
        (const float*)d_in[6], (const float*)d_in[7],
        (const float*)d_in[8], (const float*)d_in[9],
        (float*)d_out);
}